// Round 14
// baseline (299.597 us; speedup 1.0000x reference)
//
#include <hip/hip_runtime.h>
#include <hip/hip_bf16.h>
#include <hip/hip_fp16.h>

#define N_NODES 32000
#define FIN     128
#define E_EDGES 512000
#define EF_EDGES 544000
#define HC      64
#define NGRAPH  32
#define PROJ    8
#define OUT_DIM 256

// fp32 -> bf16 (RTNE) and back
static __device__ inline unsigned short f2bf(float f) {
  unsigned int x = __float_as_uint(f);
  unsigned int r = (x + 0x7fffu + ((x >> 16) & 1u)) >> 16;
  return (unsigned short)r;
}
static __device__ inline float bf2f(unsigned short u) {
  return __uint_as_float((unsigned int)u << 16);
}
// fp32 <-> fp16
static __device__ inline unsigned short f2h(float f) {
  return __half_as_ushort(__float2half(f));
}
static __device__ inline float h2f(unsigned short u) {
  return __half2float(__ushort_as_half(u));
}

// ---------------- zero deg ----------------
__global__ __launch_bounds__(256) void zero_kernel(int* __restrict__ deg) {
  deg[blockIdx.x * 256 + threadIdx.x] = 0;
}

// ---------------- degree count (int atomics) ----------------
__global__ __launch_bounds__(256) void deg_kernel(const int* __restrict__ ei,
                                                  int* __restrict__ deg) {
  int e = blockIdx.x * 256 + threadIdx.x;   // grid exactly E/256
  atomicAdd(&deg[ei[E_EDGES + e]], 1);
}

// ---------------- scan phase 1 ----------------
__global__ __launch_bounds__(256) void scan1_kernel(const int* __restrict__ deg,
                                                    int* __restrict__ offs,
                                                    int* __restrict__ bsum) {
  int idx = blockIdx.x * 256 + threadIdx.x;
  int lane = threadIdx.x & 63;
  int w = threadIdx.x >> 6;
  int v = deg[idx] + 1;   // +1 self-loop
  int s = v;
#pragma unroll
  for (int off = 1; off < 64; off <<= 1) {
    int t = __shfl_up(s, off);
    if (lane >= off) s += t;
  }
  __shared__ int wsum[4];
  if (lane == 63) wsum[w] = s;
  __syncthreads();
  int add = 0;
#pragma unroll
  for (int i = 0; i < 4; ++i) add += (i < w) ? wsum[i] : 0;
  int incl = s + add;
  offs[idx] = incl - v;
  if (threadIdx.x == 255) bsum[blockIdx.x] = incl;
}

// ---------------- scan phase 2+3 fused ----------------
__global__ __launch_bounds__(256) void scan3_kernel(const int* __restrict__ bsum,
                                                    int* __restrict__ offs,
                                                    int* __restrict__ nxt) {
  __shared__ int wsum[4];
  int tid = threadIdx.x, bid = blockIdx.x;
  int lane = tid & 63, w = tid >> 6;
  int v = (tid < bid) ? bsum[tid] : 0;
#pragma unroll
  for (int off = 1; off < 64; off <<= 1) v += __shfl_xor(v, off);
  if (lane == 0) wsum[w] = v;
  __syncthreads();
  int boff = wsum[0] + wsum[1] + wsum[2] + wsum[3];
  int idx = bid * 256 + tid;
  int o = offs[idx] + boff;
  offs[idx] = o;
  nxt[idx] = o;
  if (bid == 0 && tid == 0) offs[N_NODES] = EF_EDGES;
}

// ---------------- CSR fill ----------------
__global__ __launch_bounds__(256) void fill_kernel(const int* __restrict__ ei,
                                                   int* __restrict__ nxt,
                                                   int* __restrict__ csr_src,
                                                   int* __restrict__ csr_eid) {
  int e = blockIdx.x * 256 + threadIdx.x;
  int s, d;
  if (e < E_EDGES) { s = ei[e]; d = ei[E_EDGES + e]; }
  else             { s = e - E_EDGES; d = s; }
  int pos = atomicAdd(&nxt[d], 1);
  csr_src[pos] = s;
  csr_eid[pos] = e;
}

__device__ __forceinline__ void compute_Me(float (*sMe)[16][4],
                                           const float* __restrict__ W_e0,
                                           const float* __restrict__ a_e0,
                                           const float* __restrict__ W_eg,
                                           const float* __restrict__ a_eg) {
  int tid = threadIdx.x;
  if (tid < 192) {
    int l = tid >> 6, r6 = tid & 63, d = r6 >> 2, h = r6 & 3;
    const float* We = (l == 0) ? W_e0 : W_eg + (size_t)(l - 1) * 16 * HC;
    const float* ae = (l == 0) ? a_e0 : a_eg + (size_t)(l - 1) * 64;
    float s = 0.f;
#pragma unroll
    for (int c = 0; c < 16; ++c) s += We[d * HC + h * 16 + c] * ae[h * 16 + c];
    sMe[l][d][h] = s;
  }
  __syncthreads();
}

// ---------------- edge kernel ----------------
// lgEH layout: [(l*2+half)][pos][2 heads] fp16 (4B per edge per layer-half)
__global__ __launch_bounds__(256) void edge_kernel(const float* __restrict__ edge_attr,
                                                   const float* __restrict__ W_e0,
                                                   const float* __restrict__ a_e0,
                                                   const float* __restrict__ W_eg,
                                                   const float* __restrict__ a_eg,
                                                   const int* __restrict__ offs,
                                                   const int* __restrict__ csr_eid,
                                                   unsigned short* __restrict__ lgEH) {
  __shared__ float sMe[3][16][4];
  __shared__ float sMean[4][16];
  compute_Me(sMe, W_e0, a_e0, W_eg, a_eg);
  int b = blockIdx.x;
  int tid = threadIdx.x;
  if (b < 8000) {
    int lane = tid & 63, wv = tid >> 6;
    int n = b * 4 + wv;
    int k = lane & 15, g = lane >> 4;
    int beg = offs[n], end = offs[n + 1];
    float s = 0.f;
    int posl = -1;
    for (int i = beg + g; i < end; i += 4) {
      int e = csr_eid[i];
      if (e < E_EDGES) s += edge_attr[(size_t)e * 16 + k];
      else posl = i;
    }
    s += __shfl_xor(s, 16);
    s += __shfl_xor(s, 32);
    posl = max(posl, __shfl_xor(posl, 16));
    posl = max(posl, __shfl_xor(posl, 32));
    int degv = end - beg - 1;
    float mean = s / fmaxf((float)degv, 1.f);
    if (g == 0) sMean[wv][k] = mean;
    // same-wave LDS RAW: ordered. 6 writers: l = lane>>1, half = lane&1
    if (lane < 6) {
      int l = lane >> 1, half = lane & 1;
      float ra = 0.f, rb = 0.f;
#pragma unroll
      for (int d = 0; d < 16; ++d) {
        float a = sMean[wv][d];
        ra = fmaf(a, sMe[l][d][half * 2 + 0], ra);
        rb = fmaf(a, sMe[l][d][half * 2 + 1], rb);
      }
      unsigned int u = (unsigned int)f2h(ra) | ((unsigned int)f2h(rb) << 16);
      *(unsigned int*)&lgEH[(((size_t)l * 2 + half) * EF_EDGES + posl) * 2] = u;
    }
  } else {
    int pos = (b - 8000) * 256 + tid;
    int e = csr_eid[pos];
    if (e < E_EDGES) {
      float av[16];
      *(float4*)&av[0]  = *(const float4*)&edge_attr[(size_t)e * 16 + 0];
      *(float4*)&av[4]  = *(const float4*)&edge_attr[(size_t)e * 16 + 4];
      *(float4*)&av[8]  = *(const float4*)&edge_attr[(size_t)e * 16 + 8];
      *(float4*)&av[12] = *(const float4*)&edge_attr[(size_t)e * 16 + 12];
#pragma unroll
      for (int l = 0; l < 3; ++l) {
        float r0 = 0.f, r1 = 0.f, r2 = 0.f, r3 = 0.f;
#pragma unroll
        for (int d = 0; d < 16; ++d) {
          float a = av[d];
          r0 = fmaf(a, sMe[l][d][0], r0);
          r1 = fmaf(a, sMe[l][d][1], r1);
          r2 = fmaf(a, sMe[l][d][2], r2);
          r3 = fmaf(a, sMe[l][d][3], r3);
        }
        unsigned int u0 = (unsigned int)f2h(r0) | ((unsigned int)f2h(r1) << 16);
        unsigned int u1 = (unsigned int)f2h(r2) | ((unsigned int)f2h(r3) << 16);
        __builtin_nontemporal_store(
            u0, (unsigned int*)&lgEH[(((size_t)l * 2 + 0) * EF_EDGES + pos) * 2]);
        __builtin_nontemporal_store(
            u1, (unsigned int*)&lgEH[(((size_t)l * 2 + 1) * EF_EDGES + pos) * 2]);
      }
    }
  }
}

// ---------------- transform: xl half-tables (64B rows) + al_s side tables ----------------
// xlbH: [half][N][32] bf16 (one cache line per row). al_sh: [half][N][2] fp32.
template <int K>
__global__ __launch_bounds__(256) void transform_kernel(const float* __restrict__ A,
                                                        const float* __restrict__ W,
                                                        const float* __restrict__ a_s,
                                                        const float* __restrict__ a_d,
                                                        unsigned short* __restrict__ xlbH,
                                                        float* __restrict__ al_sh,
                                                        float* __restrict__ al_d) {
  __shared__ float sW[64][64];
  __shared__ float sA[64][65];
  int tid = threadIdx.x;
  int row0 = blockIdx.x * 64;
  int tx = tid & 15, ty = tid >> 4;
  int c0 = tx * 4, r0 = ty * 4;
  float acc[4][4] = {};
  for (int kc = 0; kc < K; kc += 64) {
    for (int i = tid; i < 1024; i += 256) {
      int kk = i >> 4, c4 = (i & 15) * 4;
      *(float4*)&sW[kk][c4] = *(const float4*)&W[(size_t)(kc + kk) * HC + c4];
    }
    for (int i = tid; i < 1024; i += 256) {
      int r = i >> 4, k4 = (i & 15) * 4;
      float4 v = *(const float4*)&A[(size_t)(row0 + r) * K + kc + k4];
      sA[r][k4 + 0] = v.x; sA[r][k4 + 1] = v.y;
      sA[r][k4 + 2] = v.z; sA[r][k4 + 3] = v.w;
    }
    __syncthreads();
#pragma unroll 8
    for (int kk = 0; kk < 64; ++kk) {
      float4 w = *(float4*)&sW[kk][c0];
      float a0 = sA[r0 + 0][kk];
      float a1 = sA[r0 + 1][kk];
      float a2 = sA[r0 + 2][kk];
      float a3 = sA[r0 + 3][kk];
      acc[0][0] = fmaf(a0, w.x, acc[0][0]); acc[0][1] = fmaf(a0, w.y, acc[0][1]);
      acc[0][2] = fmaf(a0, w.z, acc[0][2]); acc[0][3] = fmaf(a0, w.w, acc[0][3]);
      acc[1][0] = fmaf(a1, w.x, acc[1][0]); acc[1][1] = fmaf(a1, w.y, acc[1][1]);
      acc[1][2] = fmaf(a1, w.z, acc[1][2]); acc[1][3] = fmaf(a1, w.w, acc[1][3]);
      acc[2][0] = fmaf(a2, w.x, acc[2][0]); acc[2][1] = fmaf(a2, w.y, acc[2][1]);
      acc[2][2] = fmaf(a2, w.z, acc[2][2]); acc[2][3] = fmaf(a2, w.w, acc[2][3]);
      acc[3][0] = fmaf(a3, w.x, acc[3][0]); acc[3][1] = fmaf(a3, w.y, acc[3][1]);
      acc[3][2] = fmaf(a3, w.z, acc[3][2]); acc[3][3] = fmaf(a3, w.w, acc[3][3]);
    }
    __syncthreads();
  }
  float asv[4], adv[4];
#pragma unroll
  for (int j = 0; j < 4; ++j) { asv[j] = a_s[c0 + j]; adv[j] = a_d[c0 + j]; }
  int hd = tx >> 2;
  int half = c0 >> 5, cih = c0 & 31;
#pragma unroll
  for (int i = 0; i < 4; ++i) {
    int r = row0 + r0 + i;
    ushort4 u = make_ushort4(f2bf(acc[i][0]), f2bf(acc[i][1]),
                             f2bf(acc[i][2]), f2bf(acc[i][3]));
    *(ushort4*)&xlbH[((size_t)half * N_NODES + r) * 32 + cih] = u;
    float ps = acc[i][0] * asv[0] + acc[i][1] * asv[1] + acc[i][2] * asv[2] + acc[i][3] * asv[3];
    float pd = acc[i][0] * adv[0] + acc[i][1] * adv[1] + acc[i][2] * adv[2] + acc[i][3] * adv[3];
    ps += __shfl_xor(ps, 1); ps += __shfl_xor(ps, 2);
    pd += __shfl_xor(pd, 1); pd += __shfl_xor(pd, 2);
    if ((tx & 3) == 0) {
      al_sh[((size_t)(hd >> 1) * N_NODES + r) * 2 + (hd & 1)] = ps;
      al_d[(size_t)r * 4 + hd] = pd;
    }
  }
}

// ---------------- half-split gather: wave = 1 node x 32ch, 4 edge-groups x 16 lanes ----
// half = bid&1 -> alternating XCDs: each XCD's L2 sees only ONE 2.05MB xl half-table.
template <int FUSE_PROJ>
__global__ __launch_bounds__(256) void gather_kernel(const int* __restrict__ offs,
                                                     const int* __restrict__ csr_src,
                                                     const unsigned short* __restrict__ lgL,
                                                     const unsigned short* __restrict__ xlbH,
                                                     const float* __restrict__ al_sh,
                                                     const float* __restrict__ al_d,
                                                     const float* __restrict__ bias,
                                                     const float* __restrict__ Wp,
                                                     const float* __restrict__ bp,
                                                     float* __restrict__ outp) {
  int tid = threadIdx.x;
  int bid = blockIdx.x;
  int half = bid & 1;
  int n = (bid >> 1) * 4 + (tid >> 6);
  int lane = tid & 63;
  int u16 = lane & 15;
  int gr = lane >> 4;          // edge group 0..3
  int c0 = u16 * 2;            // channels within half: c0, c0+1
  int hd = u16 >> 3;           // head within half: 0/1
  const unsigned short* lgH = lgL + (size_t)half * EF_EDGES * 2;
  const unsigned short* xh  = xlbH + (size_t)half * N_NODES * 32;
  const float* ash          = al_sh + (size_t)half * N_NODES * 2;
  int beg = offs[n], end = offs[n + 1];
  float ald = al_d[(size_t)n * 4 + half * 2 + hd];
  float denom = 0.f, a0 = 0.f, a1 = 0.f;
  for (int jb = beg; jb < end; jb += 16) {   // 16 edges per wave-iter, 4 per group
    int sq[4]; unsigned short gq[4]; float pm[4];
#pragma unroll
    for (int q = 0; q < 4; ++q) {
      int j = jb + gr + q * 4;
      bool ok = j < end;
      int jc = ok ? j : beg;
      sq[q] = csr_src[jc];
      gq[q] = lgH[(size_t)jc * 2 + hd];
      pm[q] = ok ? 1.f : 0.f;
    }
    unsigned int xq[4]; float alsq[4];
#pragma unroll
    for (int q = 0; q < 4; ++q) {
      xq[q] = *(const unsigned int*)&xh[(size_t)sq[q] * 32 + c0];   // 64B row = 1 line
      alsq[q] = ash[(size_t)sq[q] * 2 + hd];
    }
#pragma unroll
    for (int q = 0; q < 4; ++q) {
      float l = h2f(gq[q]) + alsq[q] + ald;
      l = (l > 0.f) ? l : 0.2f * l;
      float p = pm[q] * __expf(l);
      denom += p;
      a0 = fmaf(p, bf2f((unsigned short)(xq[q] & 0xffff)), a0);
      a1 = fmaf(p, bf2f((unsigned short)(xq[q] >> 16)), a1);
    }
  }
  // merge 4 edge-groups (same channel map in every group)
  denom += __shfl_xor(denom, 16); denom += __shfl_xor(denom, 32);
  a0 += __shfl_xor(a0, 16); a0 += __shfl_xor(a0, 32);
  a1 += __shfl_xor(a1, 16); a1 += __shfl_xor(a1, 32);
  int gc = half * 32 + c0;   // global channel
  float hv0 = fmaxf(a0 / denom + bias[gc], 0.f);
  float hv1 = fmaxf(a1 / denom + bias[gc + 1], 0.f);
  if constexpr (!FUSE_PROJ) {
    if (gr == 0) {
      float2 o; o.x = hv0; o.y = hv1;
      *(float2*)&outp[(size_t)n * HC + gc] = o;
    }
  } else {
    // partial proj over this half's 32 channels -> pbufH[half]
    float pj[8];
#pragma unroll
    for (int j = 0; j < 8; ++j)
      pj[j] = (gr == 0) ? hv0 * Wp[gc * PROJ + j] + hv1 * Wp[(gc + 1) * PROJ + j] : 0.f;
#pragma unroll
    for (int off = 1; off < 64; off <<= 1) {
#pragma unroll
      for (int j = 0; j < 8; ++j) pj[j] += __shfl_xor(pj[j], off);
    }
    if (lane < 8) {
      float v = pj[0];
      v = (lane == 1) ? pj[1] : v;
      v = (lane == 2) ? pj[2] : v;
      v = (lane == 3) ? pj[3] : v;
      v = (lane == 4) ? pj[4] : v;
      v = (lane == 5) ? pj[5] : v;
      v = (lane == 6) ? pj[6] : v;
      v = (lane == 7) ? pj[7] : v;
      // bias/relu applied in fc1 after halves combine; store raw partial
      outp[((size_t)half * N_NODES + n) * PROJ + lane] = v;
    }
  }
}

// ---------------- fc_out stage 1: combine proj halves + bias/relu, K-chunk ----------------
__global__ __launch_bounds__(256) void fc1_kernel(const float* __restrict__ pH,
                                                  const float* __restrict__ bp,
                                                  const float* __restrict__ Wo,
                                                  float* __restrict__ part) {
  __shared__ float sp[NGRAPH][250];
  int kc = blockIdx.x;
  int ct = blockIdx.y;
  int tid = threadIdx.x;
  const float* pH1 = pH + (size_t)N_NODES * PROJ;
  for (int i = tid; i < NGRAPH * 250; i += 256) {
    int g = i / 250, kk = i % 250;
    size_t flat = (size_t)g * 8000 + kc * 250 + kk;
    sp[g][kk] = fmaxf(pH[flat] + pH1[flat] + bp[flat & 7], 0.f);
  }
  __syncthreads();
  int c = ct * 64 + (tid & 63);
  int kg = tid >> 6;
  float acc[NGRAPH] = {};
  for (int kk = kg; kk < 250; kk += 4) {
    float w = __builtin_nontemporal_load(&Wo[(size_t)(kc * 250 + kk) * OUT_DIM + c]);
#pragma unroll
    for (int g = 0; g < NGRAPH; ++g) acc[g] = fmaf(sp[g][kk], w, acc[g]);
  }
  int ch = kc * 4 + kg;
#pragma unroll
  for (int g = 0; g < NGRAPH; ++g)
    part[((size_t)ch * NGRAPH + g) * OUT_DIM + c] = acc[g];
}

// ---------------- fc_out stage 2 ----------------
__global__ __launch_bounds__(256) void fc2_kernel(const float* __restrict__ part,
                                                  const float* __restrict__ bo,
                                                  float* __restrict__ out) {
  int i = blockIdx.x * 256 + threadIdx.x;
  int g = i >> 8, c = i & 255;
  float s = bo[c];
  for (int ch = 0; ch < 128; ++ch) s += part[((size_t)ch * NGRAPH + g) * OUT_DIM + c];
  out[i] = s;
}

extern "C" void kernel_launch(void* const* d_in, const int* in_sizes, int n_in,
                              void* d_out, int out_size, void* d_ws, size_t ws_size,
                              hipStream_t stream) {
  const float* x         = (const float*)d_in[0];
  const float* edge_attr = (const float*)d_in[1];
  const float* W0        = (const float*)d_in[2];
  const float* a_s0      = (const float*)d_in[3];
  const float* a_d0      = (const float*)d_in[4];
  const float* W_e0      = (const float*)d_in[5];
  const float* a_e0      = (const float*)d_in[6];
  const float* b0        = (const float*)d_in[7];
  const float* Wg        = (const float*)d_in[8];
  const float* a_sg      = (const float*)d_in[9];
  const float* a_dg      = (const float*)d_in[10];
  const float* W_eg      = (const float*)d_in[11];
  const float* a_eg      = (const float*)d_in[12];
  const float* bg        = (const float*)d_in[13];
  const float* Wp        = (const float*)d_in[14];
  const float* bp        = (const float*)d_in[15];
  const float* Wo        = (const float*)d_in[16];
  const float* bo        = (const float*)d_in[17];
  const int*   ei        = (const int*)d_in[18];

  char* base = (char*)d_ws;
  size_t off = 0;
  auto alloc = [&](size_t bytes) -> void* {
    void* ptr = base + off;
    off = (off + bytes + 255) & ~(size_t)255;
    return ptr;
  };
  int*            deg     = (int*)alloc((size_t)N_NODES * 4);
  int*            offs    = (int*)alloc((size_t)(N_NODES + 1) * 4);
  int*            nxt     = (int*)alloc((size_t)N_NODES * 4);
  int*            bsum    = (int*)alloc(128 * 4);
  int*            csr_src = (int*)alloc((size_t)EF_EDGES * 4);
  int*            csr_eid = (int*)alloc((size_t)EF_EDGES * 4);
  unsigned short* lgEH    = (unsigned short*)alloc((size_t)6 * EF_EDGES * 2 * 2);
  unsigned short* xlbH    = (unsigned short*)alloc((size_t)2 * N_NODES * 32 * 2);
  float*          al_sh   = (float*)alloc((size_t)2 * N_NODES * 2 * 4);
  float*          al_d    = (float*)alloc((size_t)N_NODES * 4 * 4);
  float*          hA      = (float*)alloc((size_t)N_NODES * HC * 4);
  float*          hB      = (float*)alloc((size_t)N_NODES * HC * 4);
  float*          pbufH   = (float*)alloc((size_t)2 * N_NODES * PROJ * 4);
  float*          part    = (float*)alloc((size_t)128 * NGRAPH * OUT_DIM * 4);

  // ---- graph preprocessing ----
  zero_kernel<<<N_NODES / 256, 256, 0, stream>>>(deg);
  deg_kernel<<<E_EDGES / 256, 256, 0, stream>>>(ei, deg);
  scan1_kernel<<<N_NODES / 256, 256, 0, stream>>>(deg, offs, bsum);
  scan3_kernel<<<N_NODES / 256, 256, 0, stream>>>(bsum, offs, nxt);
  fill_kernel<<<EF_EDGES / 256, 256, 0, stream>>>(ei, nxt, csr_src, csr_eid);
  edge_kernel<<<8000 + 2125, 256, 0, stream>>>(edge_attr, W_e0, a_e0, W_eg, a_eg,
                                               offs, csr_eid, lgEH);
  transform_kernel<FIN><<<N_NODES / 64, 256, 0, stream>>>(x, W0, a_s0, a_d0,
                                                          xlbH, al_sh, al_d);

  // ---- layer 0 gather -> hA ----
  gather_kernel<0><<<16000, 256, 0, stream>>>(offs, csr_src, lgEH, xlbH,
                                              al_sh, al_d, b0, Wp, bp, hA);
  // ---- layer 1 ----
  transform_kernel<HC><<<N_NODES / 64, 256, 0, stream>>>(hA, Wg, a_sg, a_dg,
                                                         xlbH, al_sh, al_d);
  gather_kernel<0><<<16000, 256, 0, stream>>>(offs, csr_src, lgEH + (size_t)2 * EF_EDGES * 2,
                                              xlbH, al_sh, al_d, bg, Wp, bp, hB);
  // ---- layer 2 (proj partials fused) ----
  transform_kernel<HC><<<N_NODES / 64, 256, 0, stream>>>(hB, Wg + HC * HC, a_sg + 64,
                                                         a_dg + 64, xlbH, al_sh, al_d);
  gather_kernel<1><<<16000, 256, 0, stream>>>(offs, csr_src, lgEH + (size_t)4 * EF_EDGES * 2,
                                              xlbH, al_sh, al_d, bg + 64, Wp, bp, pbufH);

  // ---- head ----
  fc1_kernel<<<dim3(32, 4), 256, 0, stream>>>(pbufH, bp, Wo, part);
  fc2_kernel<<<NGRAPH, 256, 0, stream>>>(part, bo, (float*)d_out);
}

// Round 15
// 279.407 us; speedup vs baseline: 1.0723x; 1.0723x over previous
//
#include <hip/hip_runtime.h>
#include <hip/hip_bf16.h>
#include <hip/hip_fp16.h>

#define N_NODES 32000
#define FIN     128
#define E_EDGES 512000
#define EF_EDGES 544000
#define HC      64
#define XSTR    72          // xlb row stride in shorts: 64 bf16 ch + 4 fp32 al_s = 144B
#define NGRAPH  32
#define PROJ    8
#define OUT_DIM 256

// fp32 -> bf16 (RTNE) and back
static __device__ inline unsigned short f2bf(float f) {
  unsigned int x = __float_as_uint(f);
  unsigned int r = (x + 0x7fffu + ((x >> 16) & 1u)) >> 16;
  return (unsigned short)r;
}
static __device__ inline float bf2f(unsigned short u) {
  return __uint_as_float((unsigned int)u << 16);
}
// fp32 <-> fp16
static __device__ inline unsigned short f2h(float f) {
  return __half_as_ushort(__float2half(f));
}
static __device__ inline float h2f(unsigned short u) {
  return __half2float(__ushort_as_half(u));
}

// ---------------- zero deg ----------------
__global__ __launch_bounds__(256) void zero_kernel(int* __restrict__ deg) {
  deg[blockIdx.x * 256 + threadIdx.x] = 0;
}

// ---------------- degree count (int atomics) ----------------
__global__ __launch_bounds__(256) void deg_kernel(const int* __restrict__ ei,
                                                  int* __restrict__ deg) {
  int e = blockIdx.x * 256 + threadIdx.x;   // grid exactly E/256
  atomicAdd(&deg[ei[E_EDGES + e]], 1);
}

// ---------------- scan phase 1 ----------------
__global__ __launch_bounds__(256) void scan1_kernel(const int* __restrict__ deg,
                                                    int* __restrict__ offs,
                                                    int* __restrict__ bsum) {
  int idx = blockIdx.x * 256 + threadIdx.x;
  int lane = threadIdx.x & 63;
  int w = threadIdx.x >> 6;
  int v = deg[idx] + 1;   // +1 self-loop
  int s = v;
#pragma unroll
  for (int off = 1; off < 64; off <<= 1) {
    int t = __shfl_up(s, off);
    if (lane >= off) s += t;
  }
  __shared__ int wsum[4];
  if (lane == 63) wsum[w] = s;
  __syncthreads();
  int add = 0;
#pragma unroll
  for (int i = 0; i < 4; ++i) add += (i < w) ? wsum[i] : 0;
  int incl = s + add;
  offs[idx] = incl - v;
  if (threadIdx.x == 255) bsum[blockIdx.x] = incl;
}

// ---------------- scan phase 2+3 fused ----------------
__global__ __launch_bounds__(256) void scan3_kernel(const int* __restrict__ bsum,
                                                    int* __restrict__ offs,
                                                    int* __restrict__ nxt) {
  __shared__ int wsum[4];
  int tid = threadIdx.x, bid = blockIdx.x;
  int lane = tid & 63, w = tid >> 6;
  int v = (tid < bid) ? bsum[tid] : 0;
#pragma unroll
  for (int off = 1; off < 64; off <<= 1) v += __shfl_xor(v, off);
  if (lane == 0) wsum[w] = v;
  __syncthreads();
  int boff = wsum[0] + wsum[1] + wsum[2] + wsum[3];
  int idx = bid * 256 + tid;
  int o = offs[idx] + boff;
  offs[idx] = o;
  nxt[idx] = o;
  if (bid == 0 && tid == 0) offs[N_NODES] = EF_EDGES;
}

// ---------------- CSR fill ----------------
__global__ __launch_bounds__(256) void fill_kernel(const int* __restrict__ ei,
                                                   int* __restrict__ nxt,
                                                   int* __restrict__ csr_src,
                                                   int* __restrict__ csr_eid) {
  int e = blockIdx.x * 256 + threadIdx.x;
  int s, d;
  if (e < E_EDGES) { s = ei[e]; d = ei[E_EDGES + e]; }
  else             { s = e - E_EDGES; d = s; }
  int pos = atomicAdd(&nxt[d], 1);
  csr_src[pos] = s;
  csr_eid[pos] = e;
}

__device__ __forceinline__ void compute_Me(float (*sMe)[16][4],
                                           const float* __restrict__ W_e0,
                                           const float* __restrict__ a_e0,
                                           const float* __restrict__ W_eg,
                                           const float* __restrict__ a_eg) {
  int tid = threadIdx.x;
  if (tid < 192) {
    int l = tid >> 6, r6 = tid & 63, d = r6 >> 2, h = r6 & 3;
    const float* We = (l == 0) ? W_e0 : W_eg + (size_t)(l - 1) * 16 * HC;
    const float* ae = (l == 0) ? a_e0 : a_eg + (size_t)(l - 1) * 64;
    float s = 0.f;
#pragma unroll
    for (int c = 0; c < 16; ++c) s += We[d * HC + h * 16 + c] * ae[h * 16 + c];
    sMe[l][d][h] = s;
  }
  __syncthreads();
}

// ---------------- edge kernel: loopattr+selfloop-logits | real-edge logits ----------------
__global__ __launch_bounds__(256) void edge_kernel(const float* __restrict__ edge_attr,
                                                   const float* __restrict__ W_e0,
                                                   const float* __restrict__ a_e0,
                                                   const float* __restrict__ W_eg,
                                                   const float* __restrict__ a_eg,
                                                   const int* __restrict__ offs,
                                                   const int* __restrict__ csr_eid,
                                                   unsigned short* __restrict__ lgE) {
  __shared__ float sMe[3][16][4];
  __shared__ float sMean[4][16];
  compute_Me(sMe, W_e0, a_e0, W_eg, a_eg);
  int b = blockIdx.x;
  int tid = threadIdx.x;
  if (b < 8000) {
    int lane = tid & 63, wv = tid >> 6;
    int n = b * 4 + wv;
    int k = lane & 15, g = lane >> 4;
    int beg = offs[n], end = offs[n + 1];
    float s = 0.f;
    int posl = -1;
    for (int i = beg + g; i < end; i += 4) {
      int e = csr_eid[i];
      if (e < E_EDGES) s += edge_attr[(size_t)e * 16 + k];
      else posl = i;
    }
    s += __shfl_xor(s, 16);
    s += __shfl_xor(s, 32);
    posl = max(posl, __shfl_xor(posl, 16));
    posl = max(posl, __shfl_xor(posl, 32));
    int degv = end - beg - 1;
    float mean = s / fmaxf((float)degv, 1.f);
    if (g == 0) sMean[wv][k] = mean;
    // same-wave LDS RAW: ordered
    if (lane < 3) {
      int l = lane;
      float r0 = 0.f, r1 = 0.f, r2 = 0.f, r3 = 0.f;
#pragma unroll
      for (int d = 0; d < 16; ++d) {
        float a = sMean[wv][d];
        r0 = fmaf(a, sMe[l][d][0], r0);
        r1 = fmaf(a, sMe[l][d][1], r1);
        r2 = fmaf(a, sMe[l][d][2], r2);
        r3 = fmaf(a, sMe[l][d][3], r3);
      }
      unsigned long long u =
          (unsigned long long)f2h(r0) |
          ((unsigned long long)f2h(r1) << 16) |
          ((unsigned long long)f2h(r2) << 32) |
          ((unsigned long long)f2h(r3) << 48);
      *(unsigned long long*)&lgE[((size_t)l * EF_EDGES + posl) * 4] = u;
    }
  } else {
    int pos = (b - 8000) * 256 + tid;
    int e = csr_eid[pos];
    if (e < E_EDGES) {
      float av[16];
      *(float4*)&av[0]  = *(const float4*)&edge_attr[(size_t)e * 16 + 0];
      *(float4*)&av[4]  = *(const float4*)&edge_attr[(size_t)e * 16 + 4];
      *(float4*)&av[8]  = *(const float4*)&edge_attr[(size_t)e * 16 + 8];
      *(float4*)&av[12] = *(const float4*)&edge_attr[(size_t)e * 16 + 12];
#pragma unroll
      for (int l = 0; l < 3; ++l) {
        float r0 = 0.f, r1 = 0.f, r2 = 0.f, r3 = 0.f;
#pragma unroll
        for (int d = 0; d < 16; ++d) {
          float a = av[d];
          r0 = fmaf(a, sMe[l][d][0], r0);
          r1 = fmaf(a, sMe[l][d][1], r1);
          r2 = fmaf(a, sMe[l][d][2], r2);
          r3 = fmaf(a, sMe[l][d][3], r3);
        }
        unsigned long long u =
            (unsigned long long)f2h(r0) |
            ((unsigned long long)f2h(r1) << 16) |
            ((unsigned long long)f2h(r2) << 32) |
            ((unsigned long long)f2h(r3) << 48);
        __builtin_nontemporal_store(
            u, (unsigned long long*)&lgE[((size_t)l * EF_EDGES + pos) * 4]);
      }
    }
  }
}

// ---------------- xl(bf16)+al_s packed row = A @ W ; al_d separate ----------------
template <int K>
__global__ __launch_bounds__(256) void transform_kernel(const float* __restrict__ A,
                                                        const float* __restrict__ W,
                                                        const float* __restrict__ a_s,
                                                        const float* __restrict__ a_d,
                                                        unsigned short* __restrict__ xlb,
                                                        float* __restrict__ al_d) {
  __shared__ float sW[64][64];
  __shared__ float sA[64][65];
  int tid = threadIdx.x;
  int row0 = blockIdx.x * 64;
  int tx = tid & 15, ty = tid >> 4;
  int c0 = tx * 4, r0 = ty * 4;
  float acc[4][4] = {};
  for (int kc = 0; kc < K; kc += 64) {
    for (int i = tid; i < 1024; i += 256) {
      int kk = i >> 4, c4 = (i & 15) * 4;
      *(float4*)&sW[kk][c4] = *(const float4*)&W[(size_t)(kc + kk) * HC + c4];
    }
    for (int i = tid; i < 1024; i += 256) {
      int r = i >> 4, k4 = (i & 15) * 4;
      float4 v = *(const float4*)&A[(size_t)(row0 + r) * K + kc + k4];
      sA[r][k4 + 0] = v.x; sA[r][k4 + 1] = v.y;
      sA[r][k4 + 2] = v.z; sA[r][k4 + 3] = v.w;
    }
    __syncthreads();
#pragma unroll 8
    for (int kk = 0; kk < 64; ++kk) {
      float4 w = *(float4*)&sW[kk][c0];
      float a0 = sA[r0 + 0][kk];
      float a1 = sA[r0 + 1][kk];
      float a2 = sA[r0 + 2][kk];
      float a3 = sA[r0 + 3][kk];
      acc[0][0] = fmaf(a0, w.x, acc[0][0]); acc[0][1] = fmaf(a0, w.y, acc[0][1]);
      acc[0][2] = fmaf(a0, w.z, acc[0][2]); acc[0][3] = fmaf(a0, w.w, acc[0][3]);
      acc[1][0] = fmaf(a1, w.x, acc[1][0]); acc[1][1] = fmaf(a1, w.y, acc[1][1]);
      acc[1][2] = fmaf(a1, w.z, acc[1][2]); acc[1][3] = fmaf(a1, w.w, acc[1][3]);
      acc[2][0] = fmaf(a2, w.x, acc[2][0]); acc[2][1] = fmaf(a2, w.y, acc[2][1]);
      acc[2][2] = fmaf(a2, w.z, acc[2][2]); acc[2][3] = fmaf(a2, w.w, acc[2][3]);
      acc[3][0] = fmaf(a3, w.x, acc[3][0]); acc[3][1] = fmaf(a3, w.y, acc[3][1]);
      acc[3][2] = fmaf(a3, w.z, acc[3][2]); acc[3][3] = fmaf(a3, w.w, acc[3][3]);
    }
    __syncthreads();
  }
  float asv[4], adv[4];
#pragma unroll
  for (int j = 0; j < 4; ++j) { asv[j] = a_s[c0 + j]; adv[j] = a_d[c0 + j]; }
  int hd = tx >> 2;
#pragma unroll
  for (int i = 0; i < 4; ++i) {
    int r = row0 + r0 + i;
    ushort4 u = make_ushort4(f2bf(acc[i][0]), f2bf(acc[i][1]),
                             f2bf(acc[i][2]), f2bf(acc[i][3]));
    *(ushort4*)&xlb[(size_t)r * XSTR + c0] = u;
    float ps = acc[i][0] * asv[0] + acc[i][1] * asv[1] + acc[i][2] * asv[2] + acc[i][3] * asv[3];
    float pd = acc[i][0] * adv[0] + acc[i][1] * adv[1] + acc[i][2] * adv[2] + acc[i][3] * adv[3];
    ps += __shfl_xor(ps, 1); ps += __shfl_xor(ps, 2);
    pd += __shfl_xor(pd, 1); pd += __shfl_xor(pd, 2);
    if ((tx & 3) == 0) {
      *(float*)&xlb[(size_t)r * XSTR + 64 + hd * 2] = ps;   // al_s packed in row
      al_d[(size_t)r * 4 + hd] = pd;
    }
  }
}

// ---------------- gather: async row staging via global_load_lds ----------------
// Per 16-edge batch: 3x global_load_lds (size=16, per-lane global addr, NO dest
// VGPRs -> compiler cannot serialize), 8 stream lg loads, ONE vmcnt(0) wait,
// consume from LDS. Row = 144B = 9 x 16B chunks; chunk d16 = k*64+lane,
// e = d16/9, o = d16%9. LDS pad to 3x1024B per wave absorbs d16 in [144,192).
template <int FUSE_PROJ>
__global__ __launch_bounds__(256) void gather_kernel(const int* __restrict__ offs,
                                                     const int* __restrict__ csr_src,
                                                     const unsigned short* __restrict__ lg,
                                                     const unsigned short* __restrict__ xlb,
                                                     const float* __restrict__ al_d,
                                                     const float* __restrict__ bias,
                                                     const float* __restrict__ Wp,
                                                     const float* __restrict__ bp,
                                                     float* __restrict__ outp) {
  __shared__ char ldsraw[4 * 3072];
  int tid = threadIdx.x;
  int lane = tid & 63, wv = tid >> 6;
  int n = blockIdx.x * 4 + wv;
  int u = lane & 31;          // channel-dword index 0..31 (ch pair u*2, u*2+1)
  int hf = lane >> 5;         // edge parity
  int hd = u >> 3;            // head 0..3
  char* wbuf = ldsraw + wv * 3072;
  int beg = offs[n], end = offs[n + 1];
  float ald = al_d[(size_t)n * 4 + hd];
  float denom = 0.f, a0 = 0.f, a1 = 0.f;
  for (int jb = beg; jb < end; jb += 16) {
    // issue 3 async row-staging DMAs (no destination registers)
#pragma unroll
    for (int k = 0; k < 3; ++k) {
      int d16 = k * 64 + lane;
      d16 = (d16 < 144) ? d16 : 0;
      int e = (d16 * 57) >> 9;          // == d16/9 for d16 < 144
      int o = d16 - e * 9;
      int j = jb + e;
      j = (j < end) ? j : beg;
      int s = csr_src[j];
      const unsigned short* g = &xlb[(size_t)s * XSTR + o * 8];
      __builtin_amdgcn_global_load_lds(
          (const __attribute__((address_space(1))) void*)g,
          (__attribute__((address_space(3))) void*)(wbuf + k * 1024), 16, 0, 0);
    }
    // stream logits (L1-hot, counted by same vmcnt)
    unsigned short gq[8]; float pm[8];
#pragma unroll
    for (int q = 0; q < 8; ++q) {
      int j = jb + q * 2 + hf;
      bool ok = j < end;
      int jc = ok ? j : beg;
      gq[q] = lg[(size_t)jc * 4 + hd];
      pm[q] = ok ? 1.f : 0.f;
    }
    asm volatile("s_waitcnt vmcnt(0)" ::: "memory");
    __builtin_amdgcn_sched_barrier(0);
#pragma unroll
    for (int q = 0; q < 8; ++q) {
      int e = q * 2 + hf;
      unsigned int xx = *(const unsigned int*)(wbuf + e * 144 + u * 4);
      float als = *(const float*)(wbuf + e * 144 + 128 + hd * 4);
      float l = h2f(gq[q]) + als + ald;
      l = (l > 0.f) ? l : 0.2f * l;
      float p = pm[q] * __expf(l);
      denom += p;
      a0 = fmaf(p, bf2f((unsigned short)(xx & 0xffff)), a0);
      a1 = fmaf(p, bf2f((unsigned short)(xx >> 16)), a1);
    }
  }
  // merge halves (plain sums — no max tracking)
  denom += __shfl_xor(denom, 32);
  a0 += __shfl_xor(a0, 32);
  a1 += __shfl_xor(a1, 32);
  int c0 = u * 2;
  float hv0 = fmaxf(a0 / denom + bias[c0], 0.f);
  float hv1 = fmaxf(a1 / denom + bias[c0 + 1], 0.f);
  if constexpr (!FUSE_PROJ) {
    if (hf == 0) {
      float2 o; o.x = hv0; o.y = hv1;
      *(float2*)&outp[(size_t)n * HC + c0] = o;
    }
  } else {
    float pj[8];
#pragma unroll
    for (int j = 0; j < 8; ++j)
      pj[j] = (hf == 0) ? hv0 * Wp[c0 * PROJ + j] + hv1 * Wp[(c0 + 1) * PROJ + j] : 0.f;
#pragma unroll
    for (int off = 1; off < 64; off <<= 1) {
#pragma unroll
      for (int j = 0; j < 8; ++j) pj[j] += __shfl_xor(pj[j], off);
    }
    if (lane < 8) {
      float v = pj[0];
      v = (lane == 1) ? pj[1] : v;
      v = (lane == 2) ? pj[2] : v;
      v = (lane == 3) ? pj[3] : v;
      v = (lane == 4) ? pj[4] : v;
      v = (lane == 5) ? pj[5] : v;
      v = (lane == 6) ? pj[6] : v;
      v = (lane == 7) ? pj[7] : v;
      outp[(size_t)n * PROJ + lane] = fmaxf(v + bp[lane], 0.f);
    }
  }
}

// ---------------- fc_out stage 1 ----------------
__global__ __launch_bounds__(256) void fc1_kernel(const float* __restrict__ p,
                                                  const float* __restrict__ Wo,
                                                  float* __restrict__ part) {
  __shared__ float sp[NGRAPH][250];
  int kc = blockIdx.x;
  int ct = blockIdx.y;
  int tid = threadIdx.x;
  for (int i = tid; i < NGRAPH * 250; i += 256) {
    int g = i / 250, kk = i % 250;
    sp[g][kk] = p[(size_t)g * 8000 + kc * 250 + kk];
  }
  __syncthreads();
  int c = ct * 64 + (tid & 63);
  int kg = tid >> 6;
  float acc[NGRAPH] = {};
  for (int kk = kg; kk < 250; kk += 4) {
    float w = __builtin_nontemporal_load(&Wo[(size_t)(kc * 250 + kk) * OUT_DIM + c]);
#pragma unroll
    for (int g = 0; g < NGRAPH; ++g) acc[g] = fmaf(sp[g][kk], w, acc[g]);
  }
  int ch = kc * 4 + kg;
#pragma unroll
  for (int g = 0; g < NGRAPH; ++g)
    part[((size_t)ch * NGRAPH + g) * OUT_DIM + c] = acc[g];
}

// ---------------- fc_out stage 2 ----------------
__global__ __launch_bounds__(256) void fc2_kernel(const float* __restrict__ part,
                                                  const float* __restrict__ bo,
                                                  float* __restrict__ out) {
  int i = blockIdx.x * 256 + threadIdx.x;
  int g = i >> 8, c = i & 255;
  float s = bo[c];
  for (int ch = 0; ch < 128; ++ch) s += part[((size_t)ch * NGRAPH + g) * OUT_DIM + c];
  out[i] = s;
}

extern "C" void kernel_launch(void* const* d_in, const int* in_sizes, int n_in,
                              void* d_out, int out_size, void* d_ws, size_t ws_size,
                              hipStream_t stream) {
  const float* x         = (const float*)d_in[0];
  const float* edge_attr = (const float*)d_in[1];
  const float* W0        = (const float*)d_in[2];
  const float* a_s0      = (const float*)d_in[3];
  const float* a_d0      = (const float*)d_in[4];
  const float* W_e0      = (const float*)d_in[5];
  const float* a_e0      = (const float*)d_in[6];
  const float* b0        = (const float*)d_in[7];
  const float* Wg        = (const float*)d_in[8];
  const float* a_sg      = (const float*)d_in[9];
  const float* a_dg      = (const float*)d_in[10];
  const float* W_eg      = (const float*)d_in[11];
  const float* a_eg      = (const float*)d_in[12];
  const float* bg        = (const float*)d_in[13];
  const float* Wp        = (const float*)d_in[14];
  const float* bp        = (const float*)d_in[15];
  const float* Wo        = (const float*)d_in[16];
  const float* bo        = (const float*)d_in[17];
  const int*   ei        = (const int*)d_in[18];

  char* base = (char*)d_ws;
  size_t off = 0;
  auto alloc = [&](size_t bytes) -> void* {
    void* ptr = base + off;
    off = (off + bytes + 255) & ~(size_t)255;
    return ptr;
  };
  int*            deg     = (int*)alloc((size_t)N_NODES * 4);
  int*            offs    = (int*)alloc((size_t)(N_NODES + 1) * 4);
  int*            nxt     = (int*)alloc((size_t)N_NODES * 4);
  int*            bsum    = (int*)alloc(128 * 4);
  int*            csr_src = (int*)alloc((size_t)EF_EDGES * 4);
  int*            csr_eid = (int*)alloc((size_t)EF_EDGES * 4);
  unsigned short* lgE     = (unsigned short*)alloc((size_t)3 * EF_EDGES * 4 * 2);
  unsigned short* xlb     = (unsigned short*)alloc((size_t)N_NODES * XSTR * 2);
  float*          al_d    = (float*)alloc((size_t)N_NODES * 4 * 4);
  float*          hA      = (float*)alloc((size_t)N_NODES * HC * 4);
  float*          hB      = (float*)alloc((size_t)N_NODES * HC * 4);
  float*          pbuf    = (float*)alloc((size_t)N_NODES * PROJ * 4);
  float*          part    = (float*)alloc((size_t)128 * NGRAPH * OUT_DIM * 4);

  // ---- graph preprocessing ----
  zero_kernel<<<N_NODES / 256, 256, 0, stream>>>(deg);
  deg_kernel<<<E_EDGES / 256, 256, 0, stream>>>(ei, deg);
  scan1_kernel<<<N_NODES / 256, 256, 0, stream>>>(deg, offs, bsum);
  scan3_kernel<<<N_NODES / 256, 256, 0, stream>>>(bsum, offs, nxt);
  fill_kernel<<<EF_EDGES / 256, 256, 0, stream>>>(ei, nxt, csr_src, csr_eid);
  edge_kernel<<<8000 + 2125, 256, 0, stream>>>(edge_attr, W_e0, a_e0, W_eg, a_eg,
                                               offs, csr_eid, lgE);
  transform_kernel<FIN><<<N_NODES / 64, 256, 0, stream>>>(x, W0, a_s0, a_d0, xlb, al_d);

  // ---- layer 0 gather -> hA ----
  gather_kernel<0><<<N_NODES / 4, 256, 0, stream>>>(offs, csr_src, lgE, xlb,
                                                    al_d, b0, Wp, bp, hA);
  // ---- layer 1 ----
  transform_kernel<HC><<<N_NODES / 64, 256, 0, stream>>>(hA, Wg, a_sg, a_dg, xlb, al_d);
  gather_kernel<0><<<N_NODES / 4, 256, 0, stream>>>(offs, csr_src, lgE + (size_t)EF_EDGES * 4,
                                                    xlb, al_d, bg, Wp, bp, hB);
  // ---- layer 2 (proj fused) ----
  transform_kernel<HC><<<N_NODES / 64, 256, 0, stream>>>(hB, Wg + HC * HC, a_sg + 64,
                                                         a_dg + 64, xlb, al_d);
  gather_kernel<1><<<N_NODES / 4, 256, 0, stream>>>(offs, csr_src, lgE + (size_t)2 * EF_EDGES * 4,
                                                    xlb, al_d, bg + 64, Wp, bp, pbuf);

  // ---- head ----
  fc1_kernel<<<dim3(32, 4), 256, 0, stream>>>(pbuf, Wo, part);
  fc2_kernel<<<NGRAPH, 256, 0, stream>>>(part, bo, (float*)d_out);
}

// Round 16
// 268.736 us; speedup vs baseline: 1.1148x; 1.0397x over previous
//
#include <hip/hip_runtime.h>
#include <hip/hip_bf16.h>
#include <hip/hip_fp16.h>

#define N_NODES 32000
#define FIN     128
#define E_EDGES 512000
#define EF_EDGES 544000
#define HC      64
#define XSTR    72          // xlb row stride in shorts: 64 bf16 ch + 4 fp32 al_s = 144B
#define NGRAPH  32
#define PROJ    8
#define OUT_DIM 256

// fp32 -> bf16 (RTNE) and back
static __device__ inline unsigned short f2bf(float f) {
  unsigned int x = __float_as_uint(f);
  unsigned int r = (x + 0x7fffu + ((x >> 16) & 1u)) >> 16;
  return (unsigned short)r;
}
static __device__ inline float bf2f(unsigned short u) {
  return __uint_as_float((unsigned int)u << 16);
}
// fp32 <-> fp16
static __device__ inline unsigned short f2h(float f) {
  return __half_as_ushort(__float2half(f));
}
static __device__ inline float h2f(unsigned short u) {
  return __half2float(__ushort_as_half(u));
}

// ---------------- zero deg ----------------
__global__ __launch_bounds__(256) void zero_kernel(int* __restrict__ deg) {
  deg[blockIdx.x * 256 + threadIdx.x] = 0;
}

// ---------------- degree count (int atomics) ----------------
__global__ __launch_bounds__(256) void deg_kernel(const int* __restrict__ ei,
                                                  int* __restrict__ deg) {
  int e = blockIdx.x * 256 + threadIdx.x;   // grid exactly E/256
  atomicAdd(&deg[ei[E_EDGES + e]], 1);
}

// ---------------- scan phase 1 ----------------
__global__ __launch_bounds__(256) void scan1_kernel(const int* __restrict__ deg,
                                                    int* __restrict__ offs,
                                                    int* __restrict__ bsum) {
  int idx = blockIdx.x * 256 + threadIdx.x;
  int lane = threadIdx.x & 63;
  int w = threadIdx.x >> 6;
  int v = deg[idx] + 1;   // +1 self-loop
  int s = v;
#pragma unroll
  for (int off = 1; off < 64; off <<= 1) {
    int t = __shfl_up(s, off);
    if (lane >= off) s += t;
  }
  __shared__ int wsum[4];
  if (lane == 63) wsum[w] = s;
  __syncthreads();
  int add = 0;
#pragma unroll
  for (int i = 0; i < 4; ++i) add += (i < w) ? wsum[i] : 0;
  int incl = s + add;
  offs[idx] = incl - v;
  if (threadIdx.x == 255) bsum[blockIdx.x] = incl;
}

// ---------------- scan phase 2+3 fused ----------------
__global__ __launch_bounds__(256) void scan3_kernel(const int* __restrict__ bsum,
                                                    int* __restrict__ offs,
                                                    int* __restrict__ nxt) {
  __shared__ int wsum[4];
  int tid = threadIdx.x, bid = blockIdx.x;
  int lane = tid & 63, w = tid >> 6;
  int v = (tid < bid) ? bsum[tid] : 0;
#pragma unroll
  for (int off = 1; off < 64; off <<= 1) v += __shfl_xor(v, off);
  if (lane == 0) wsum[w] = v;
  __syncthreads();
  int boff = wsum[0] + wsum[1] + wsum[2] + wsum[3];
  int idx = bid * 256 + tid;
  int o = offs[idx] + boff;
  offs[idx] = o;
  nxt[idx] = o;
  if (bid == 0 && tid == 0) offs[N_NODES] = EF_EDGES;
}

// ---------------- CSR fill ----------------
__global__ __launch_bounds__(256) void fill_kernel(const int* __restrict__ ei,
                                                   int* __restrict__ nxt,
                                                   int* __restrict__ csr_src,
                                                   int* __restrict__ csr_eid) {
  int e = blockIdx.x * 256 + threadIdx.x;
  int s, d;
  if (e < E_EDGES) { s = ei[e]; d = ei[E_EDGES + e]; }
  else             { s = e - E_EDGES; d = s; }
  int pos = atomicAdd(&nxt[d], 1);
  csr_src[pos] = s;
  csr_eid[pos] = e;
}

__device__ __forceinline__ void compute_Me(float (*sMe)[16][4],
                                           const float* __restrict__ W_e0,
                                           const float* __restrict__ a_e0,
                                           const float* __restrict__ W_eg,
                                           const float* __restrict__ a_eg) {
  int tid = threadIdx.x;
  if (tid < 192) {
    int l = tid >> 6, r6 = tid & 63, d = r6 >> 2, h = r6 & 3;
    const float* We = (l == 0) ? W_e0 : W_eg + (size_t)(l - 1) * 16 * HC;
    const float* ae = (l == 0) ? a_e0 : a_eg + (size_t)(l - 1) * 64;
    float s = 0.f;
#pragma unroll
    for (int c = 0; c < 16; ++c) s += We[d * HC + h * 16 + c] * ae[h * 16 + c];
    sMe[l][d][h] = s;
  }
  __syncthreads();
}

// ---------------- edge kernel: loopattr+selfloop-logits | real-edge logits ----------------
__global__ __launch_bounds__(256) void edge_kernel(const float* __restrict__ edge_attr,
                                                   const float* __restrict__ W_e0,
                                                   const float* __restrict__ a_e0,
                                                   const float* __restrict__ W_eg,
                                                   const float* __restrict__ a_eg,
                                                   const int* __restrict__ offs,
                                                   const int* __restrict__ csr_eid,
                                                   unsigned short* __restrict__ lgE) {
  __shared__ float sMe[3][16][4];
  __shared__ float sMean[4][16];
  compute_Me(sMe, W_e0, a_e0, W_eg, a_eg);
  int b = blockIdx.x;
  int tid = threadIdx.x;
  if (b < 8000) {
    int lane = tid & 63, wv = tid >> 6;
    int n = b * 4 + wv;
    int k = lane & 15, g = lane >> 4;
    int beg = offs[n], end = offs[n + 1];
    float s = 0.f;
    int posl = -1;
    for (int i = beg + g; i < end; i += 4) {
      int e = csr_eid[i];
      if (e < E_EDGES) s += edge_attr[(size_t)e * 16 + k];
      else posl = i;
    }
    s += __shfl_xor(s, 16);
    s += __shfl_xor(s, 32);
    posl = max(posl, __shfl_xor(posl, 16));
    posl = max(posl, __shfl_xor(posl, 32));
    int degv = end - beg - 1;
    float mean = s / fmaxf((float)degv, 1.f);
    if (g == 0) sMean[wv][k] = mean;
    // same-wave LDS RAW: ordered
    if (lane < 3) {
      int l = lane;
      float r0 = 0.f, r1 = 0.f, r2 = 0.f, r3 = 0.f;
#pragma unroll
      for (int d = 0; d < 16; ++d) {
        float a = sMean[wv][d];
        r0 = fmaf(a, sMe[l][d][0], r0);
        r1 = fmaf(a, sMe[l][d][1], r1);
        r2 = fmaf(a, sMe[l][d][2], r2);
        r3 = fmaf(a, sMe[l][d][3], r3);
      }
      unsigned long long u =
          (unsigned long long)f2h(r0) |
          ((unsigned long long)f2h(r1) << 16) |
          ((unsigned long long)f2h(r2) << 32) |
          ((unsigned long long)f2h(r3) << 48);
      *(unsigned long long*)&lgE[((size_t)l * EF_EDGES + posl) * 4] = u;
    }
  } else {
    int pos = (b - 8000) * 256 + tid;
    int e = csr_eid[pos];
    if (e < E_EDGES) {
      float av[16];
      *(float4*)&av[0]  = *(const float4*)&edge_attr[(size_t)e * 16 + 0];
      *(float4*)&av[4]  = *(const float4*)&edge_attr[(size_t)e * 16 + 4];
      *(float4*)&av[8]  = *(const float4*)&edge_attr[(size_t)e * 16 + 8];
      *(float4*)&av[12] = *(const float4*)&edge_attr[(size_t)e * 16 + 12];
#pragma unroll
      for (int l = 0; l < 3; ++l) {
        float r0 = 0.f, r1 = 0.f, r2 = 0.f, r3 = 0.f;
#pragma unroll
        for (int d = 0; d < 16; ++d) {
          float a = av[d];
          r0 = fmaf(a, sMe[l][d][0], r0);
          r1 = fmaf(a, sMe[l][d][1], r1);
          r2 = fmaf(a, sMe[l][d][2], r2);
          r3 = fmaf(a, sMe[l][d][3], r3);
        }
        unsigned long long u =
            (unsigned long long)f2h(r0) |
            ((unsigned long long)f2h(r1) << 16) |
            ((unsigned long long)f2h(r2) << 32) |
            ((unsigned long long)f2h(r3) << 48);
        __builtin_nontemporal_store(
            u, (unsigned long long*)&lgE[((size_t)l * EF_EDGES + pos) * 4]);
      }
    }
  }
}

// ---------------- xl(bf16)+al_s packed row = A @ W ; al_d separate ----------------
template <int K>
__global__ __launch_bounds__(256) void transform_kernel(const float* __restrict__ A,
                                                        const float* __restrict__ W,
                                                        const float* __restrict__ a_s,
                                                        const float* __restrict__ a_d,
                                                        unsigned short* __restrict__ xlb,
                                                        float* __restrict__ al_d) {
  __shared__ float sW[64][64];
  __shared__ float sA[64][65];
  int tid = threadIdx.x;
  int row0 = blockIdx.x * 64;
  int tx = tid & 15, ty = tid >> 4;
  int c0 = tx * 4, r0 = ty * 4;
  float acc[4][4] = {};
  for (int kc = 0; kc < K; kc += 64) {
    for (int i = tid; i < 1024; i += 256) {
      int kk = i >> 4, c4 = (i & 15) * 4;
      *(float4*)&sW[kk][c4] = *(const float4*)&W[(size_t)(kc + kk) * HC + c4];
    }
    for (int i = tid; i < 1024; i += 256) {
      int r = i >> 4, k4 = (i & 15) * 4;
      float4 v = *(const float4*)&A[(size_t)(row0 + r) * K + kc + k4];
      sA[r][k4 + 0] = v.x; sA[r][k4 + 1] = v.y;
      sA[r][k4 + 2] = v.z; sA[r][k4 + 3] = v.w;
    }
    __syncthreads();
#pragma unroll 8
    for (int kk = 0; kk < 64; ++kk) {
      float4 w = *(float4*)&sW[kk][c0];
      float a0 = sA[r0 + 0][kk];
      float a1 = sA[r0 + 1][kk];
      float a2 = sA[r0 + 2][kk];
      float a3 = sA[r0 + 3][kk];
      acc[0][0] = fmaf(a0, w.x, acc[0][0]); acc[0][1] = fmaf(a0, w.y, acc[0][1]);
      acc[0][2] = fmaf(a0, w.z, acc[0][2]); acc[0][3] = fmaf(a0, w.w, acc[0][3]);
      acc[1][0] = fmaf(a1, w.x, acc[1][0]); acc[1][1] = fmaf(a1, w.y, acc[1][1]);
      acc[1][2] = fmaf(a1, w.z, acc[1][2]); acc[1][3] = fmaf(a1, w.w, acc[1][3]);
      acc[2][0] = fmaf(a2, w.x, acc[2][0]); acc[2][1] = fmaf(a2, w.y, acc[2][1]);
      acc[2][2] = fmaf(a2, w.z, acc[2][2]); acc[2][3] = fmaf(a2, w.w, acc[2][3]);
      acc[3][0] = fmaf(a3, w.x, acc[3][0]); acc[3][1] = fmaf(a3, w.y, acc[3][1]);
      acc[3][2] = fmaf(a3, w.z, acc[3][2]); acc[3][3] = fmaf(a3, w.w, acc[3][3]);
    }
    __syncthreads();
  }
  float asv[4], adv[4];
#pragma unroll
  for (int j = 0; j < 4; ++j) { asv[j] = a_s[c0 + j]; adv[j] = a_d[c0 + j]; }
  int hd = tx >> 2;
#pragma unroll
  for (int i = 0; i < 4; ++i) {
    int r = row0 + r0 + i;
    ushort4 u = make_ushort4(f2bf(acc[i][0]), f2bf(acc[i][1]),
                             f2bf(acc[i][2]), f2bf(acc[i][3]));
    *(ushort4*)&xlb[(size_t)r * XSTR + c0] = u;
    float ps = acc[i][0] * asv[0] + acc[i][1] * asv[1] + acc[i][2] * asv[2] + acc[i][3] * asv[3];
    float pd = acc[i][0] * adv[0] + acc[i][1] * adv[1] + acc[i][2] * adv[2] + acc[i][3] * adv[3];
    ps += __shfl_xor(ps, 1); ps += __shfl_xor(ps, 2);
    pd += __shfl_xor(pd, 1); pd += __shfl_xor(pd, 2);
    if ((tx & 3) == 0) {
      *(float*)&xlb[(size_t)r * XSTR + 64 + hd * 2] = ps;   // al_s packed in row
      al_d[(size_t)r * 4 + hd] = pd;
    }
  }
}

// ---------------- phase-split gather: lanes = (edge,head) then (channel,parity) ----
// Phase A: lane q*4+hd computes p for (edge jb+q, head hd) ONCE (was 8x redundant);
// lg load fully coalesced (128B/iter). Phase B: p/src broadcast via shfl; row reads
// 1-row-per-instr coalesced. Per-head denom via stride-4..32 xor-reduce.
template <int FUSE_PROJ>
__global__ __launch_bounds__(256) void gather_kernel(const int* __restrict__ offs,
                                                     const int* __restrict__ csr_src,
                                                     const unsigned short* __restrict__ lg,
                                                     const unsigned short* __restrict__ xlb,
                                                     const float* __restrict__ al_d,
                                                     const float* __restrict__ bias,
                                                     const float* __restrict__ Wp,
                                                     const float* __restrict__ bp,
                                                     float* __restrict__ outp) {
  int tid = threadIdx.x;
  int lane = tid & 63;
  int n = blockIdx.x * 4 + (tid >> 6);
  int q16 = lane >> 2, hd4 = lane & 3;   // phase A: edge-in-batch, head
  int eu = lane >> 5, v = lane & 31;     // phase B: edge parity, channel pair
  int hdB = v >> 3;                      // head owning channel pair v
  int beg = offs[n], end = offs[n + 1];
  float ald = al_d[(size_t)n * 4 + hd4];
  float denq = 0.f, a0 = 0.f, a1 = 0.f;
  for (int jb = beg; jb < end; jb += 16) {
    // ---- phase A: one (edge,head) per lane ----
    int j = jb + q16;
    bool ok = j < end;
    int jc = ok ? j : beg;
    int sq = csr_src[jc];
    unsigned short lgv = lg[(size_t)jc * 4 + hd4];   // coalesced 128B
    const unsigned short* rowA = &xlb[(size_t)sq * XSTR];
    float als = *(const float*)&rowA[64 + hd4 * 2];
    float l = h2f(lgv) + als + ald;
    l = fmaxf(l, 0.2f * l);                          // leaky_relu, branch-free
    float p = ok ? __expf(l) : 0.f;
    denq += p;
    // ---- phase B: channels; 2 edges per k-step via parity ----
#pragma unroll
    for (int k = 0; k < 8; ++k) {
      int e = k * 2 + eu;
      int se = __shfl(sq, e * 4);                    // src of edge e
      float pe = __shfl(p, e * 4 + hdB);             // p of (e, head of v)
      unsigned int xx = *(const unsigned int*)&xlb[(size_t)se * XSTR + 2 * v];
      a0 = fmaf(pe, bf2f((unsigned short)(xx & 0xffff)), a0);
      a1 = fmaf(pe, bf2f((unsigned short)(xx >> 16)), a1);
    }
  }
  // per-head denom: sum over the 16 q-lanes of each head
  denq += __shfl_xor(denq, 4);
  denq += __shfl_xor(denq, 8);
  denq += __shfl_xor(denq, 16);
  denq += __shfl_xor(denq, 32);
  float denom = __shfl(denq, hdB);   // lane hdB (q=0) holds head hdB's denom
  // merge edge-parity halves
  a0 += __shfl_xor(a0, 32);
  a1 += __shfl_xor(a1, 32);
  int c0 = v * 2;
  float hv0 = fmaxf(a0 / denom + bias[c0], 0.f);
  float hv1 = fmaxf(a1 / denom + bias[c0 + 1], 0.f);
  if constexpr (!FUSE_PROJ) {
    if (eu == 0) {
      float2 o; o.x = hv0; o.y = hv1;
      *(float2*)&outp[(size_t)n * HC + c0] = o;
    }
  } else {
    float pj[8];
#pragma unroll
    for (int j = 0; j < 8; ++j)
      pj[j] = (eu == 0) ? hv0 * Wp[c0 * PROJ + j] + hv1 * Wp[(c0 + 1) * PROJ + j] : 0.f;
#pragma unroll
    for (int off = 1; off < 64; off <<= 1) {
#pragma unroll
      for (int j = 0; j < 8; ++j) pj[j] += __shfl_xor(pj[j], off);
    }
    if (lane < 8) {
      float val = pj[0];
      val = (lane == 1) ? pj[1] : val;
      val = (lane == 2) ? pj[2] : val;
      val = (lane == 3) ? pj[3] : val;
      val = (lane == 4) ? pj[4] : val;
      val = (lane == 5) ? pj[5] : val;
      val = (lane == 6) ? pj[6] : val;
      val = (lane == 7) ? pj[7] : val;
      outp[(size_t)n * PROJ + lane] = fmaxf(val + bp[lane], 0.f);
    }
  }
}

// ---------------- fc_out stage 1 ----------------
__global__ __launch_bounds__(256) void fc1_kernel(const float* __restrict__ p,
                                                  const float* __restrict__ Wo,
                                                  float* __restrict__ part) {
  __shared__ float sp[NGRAPH][250];
  int kc = blockIdx.x;
  int ct = blockIdx.y;
  int tid = threadIdx.x;
  for (int i = tid; i < NGRAPH * 250; i += 256) {
    int g = i / 250, kk = i % 250;
    sp[g][kk] = p[(size_t)g * 8000 + kc * 250 + kk];
  }
  __syncthreads();
  int c = ct * 64 + (tid & 63);
  int kg = tid >> 6;
  float acc[NGRAPH] = {};
  for (int kk = kg; kk < 250; kk += 4) {
    float w = __builtin_nontemporal_load(&Wo[(size_t)(kc * 250 + kk) * OUT_DIM + c]);
#pragma unroll
    for (int g = 0; g < NGRAPH; ++g) acc[g] = fmaf(sp[g][kk], w, acc[g]);
  }
  int ch = kc * 4 + kg;
#pragma unroll
  for (int g = 0; g < NGRAPH; ++g)
    part[((size_t)ch * NGRAPH + g) * OUT_DIM + c] = acc[g];
}

// ---------------- fc_out stage 2 ----------------
__global__ __launch_bounds__(256) void fc2_kernel(const float* __restrict__ part,
                                                  const float* __restrict__ bo,
                                                  float* __restrict__ out) {
  int i = blockIdx.x * 256 + threadIdx.x;
  int g = i >> 8, c = i & 255;
  float s = bo[c];
  for (int ch = 0; ch < 128; ++ch) s += part[((size_t)ch * NGRAPH + g) * OUT_DIM + c];
  out[i] = s;
}

extern "C" void kernel_launch(void* const* d_in, const int* in_sizes, int n_in,
                              void* d_out, int out_size, void* d_ws, size_t ws_size,
                              hipStream_t stream) {
  const float* x         = (const float*)d_in[0];
  const float* edge_attr = (const float*)d_in[1];
  const float* W0        = (const float*)d_in[2];
  const float* a_s0      = (const float*)d_in[3];
  const float* a_d0      = (const float*)d_in[4];
  const float* W_e0      = (const float*)d_in[5];
  const float* a_e0      = (const float*)d_in[6];
  const float* b0        = (const float*)d_in[7];
  const float* Wg        = (const float*)d_in[8];
  const float* a_sg      = (const float*)d_in[9];
  const float* a_dg      = (const float*)d_in[10];
  const float* W_eg      = (const float*)d_in[11];
  const float* a_eg      = (const float*)d_in[12];
  const float* bg        = (const float*)d_in[13];
  const float* Wp        = (const float*)d_in[14];
  const float* bp        = (const float*)d_in[15];
  const float* Wo        = (const float*)d_in[16];
  const float* bo        = (const float*)d_in[17];
  const int*   ei        = (const int*)d_in[18];

  char* base = (char*)d_ws;
  size_t off = 0;
  auto alloc = [&](size_t bytes) -> void* {
    void* ptr = base + off;
    off = (off + bytes + 255) & ~(size_t)255;
    return ptr;
  };
  int*            deg     = (int*)alloc((size_t)N_NODES * 4);
  int*            offs    = (int*)alloc((size_t)(N_NODES + 1) * 4);
  int*            nxt     = (int*)alloc((size_t)N_NODES * 4);
  int*            bsum    = (int*)alloc(128 * 4);
  int*            csr_src = (int*)alloc((size_t)EF_EDGES * 4);
  int*            csr_eid = (int*)alloc((size_t)EF_EDGES * 4);
  unsigned short* lgE     = (unsigned short*)alloc((size_t)3 * EF_EDGES * 4 * 2);
  unsigned short* xlb     = (unsigned short*)alloc((size_t)N_NODES * XSTR * 2);
  float*          al_d    = (float*)alloc((size_t)N_NODES * 4 * 4);
  float*          hA      = (float*)alloc((size_t)N_NODES * HC * 4);
  float*          hB      = (float*)alloc((size_t)N_NODES * HC * 4);
  float*          pbuf    = (float*)alloc((size_t)N_NODES * PROJ * 4);
  float*          part    = (float*)alloc((size_t)128 * NGRAPH * OUT_DIM * 4);

  // ---- graph preprocessing ----
  zero_kernel<<<N_NODES / 256, 256, 0, stream>>>(deg);
  deg_kernel<<<E_EDGES / 256, 256, 0, stream>>>(ei, deg);
  scan1_kernel<<<N_NODES / 256, 256, 0, stream>>>(deg, offs, bsum);
  scan3_kernel<<<N_NODES / 256, 256, 0, stream>>>(bsum, offs, nxt);
  fill_kernel<<<EF_EDGES / 256, 256, 0, stream>>>(ei, nxt, csr_src, csr_eid);
  edge_kernel<<<8000 + 2125, 256, 0, stream>>>(edge_attr, W_e0, a_e0, W_eg, a_eg,
                                               offs, csr_eid, lgE);
  transform_kernel<FIN><<<N_NODES / 64, 256, 0, stream>>>(x, W0, a_s0, a_d0, xlb, al_d);

  // ---- layer 0 gather -> hA ----
  gather_kernel<0><<<N_NODES / 4, 256, 0, stream>>>(offs, csr_src, lgE, xlb,
                                                    al_d, b0, Wp, bp, hA);
  // ---- layer 1 ----
  transform_kernel<HC><<<N_NODES / 64, 256, 0, stream>>>(hA, Wg, a_sg, a_dg, xlb, al_d);
  gather_kernel<0><<<N_NODES / 4, 256, 0, stream>>>(offs, csr_src, lgE + (size_t)EF_EDGES * 4,
                                                    xlb, al_d, bg, Wp, bp, hB);
  // ---- layer 2 (proj fused) ----
  transform_kernel<HC><<<N_NODES / 64, 256, 0, stream>>>(hB, Wg + HC * HC, a_sg + 64,
                                                         a_dg + 64, xlb, al_d);
  gather_kernel<1><<<N_NODES / 4, 256, 0, stream>>>(offs, csr_src, lgE + (size_t)2 * EF_EDGES * 4,
                                                    xlb, al_d, bg + 64, Wp, bp, pbuf);

  // ---- head ----
  fc1_kernel<<<dim3(32, 4), 256, 0, stream>>>(pbuf, Wo, part);
  fc2_kernel<<<NGRAPH, 256, 0, stream>>>(part, bo, (float*)d_out);
}